// Round 8
// baseline (496.610 us; speedup 1.0000x reference)
//
#include <hip/hip_runtime.h>
#include <hip/hip_fp16.h>

#define HD 128      // hidden dim
#define CHUNK 4096  // edges per coarse-sort block
#define MAXNB 512   // max coarse buckets (N/256; N=100K -> 391)

typedef _Float16 f16x8 __attribute__((ext_vector_type(8)));
typedef float f32x4 __attribute__((ext_vector_type(4)));

// ---- merged: src out-degree (4-replica global atomics) + coarse dst histogram ----
__global__ __launch_bounds__(256) void hist_count(const int* __restrict__ src,
                                                  const int* __restrict__ dst,
                                                  unsigned int* __restrict__ cnt4s,
                                                  unsigned int* __restrict__ gHist,
                                                  int N, int NB, int NC, int E) {
    __shared__ unsigned int hist[MAXNB];
    for (int b = threadIdx.x; b < NB; b += 256) hist[b] = 0;
    __syncthreads();
    int base = blockIdx.x * CHUNK;
    int e0 = base + 4 * threadIdx.x;
#pragma unroll
    for (int it = 0; it < CHUNK / 1024; ++it, e0 += 1024) {
        if (e0 + 3 < E) {
            int4 s4 = *(const int4*)(src + e0);
            int4 d4 = *(const int4*)(dst + e0);
            atomicAdd(&cnt4s[0 * N + s4.x], 1u);
            atomicAdd(&cnt4s[1 * N + s4.y], 1u);
            atomicAdd(&cnt4s[2 * N + s4.z], 1u);
            atomicAdd(&cnt4s[3 * N + s4.w], 1u);
            atomicAdd(&hist[d4.x >> 8], 1u);
            atomicAdd(&hist[d4.y >> 8], 1u);
            atomicAdd(&hist[d4.z >> 8], 1u);
            atomicAdd(&hist[d4.w >> 8], 1u);
        } else {
            for (int j = 0; j < 4; ++j)
                if (e0 + j < E) {
                    atomicAdd(&cnt4s[j * N + src[e0 + j]], 1u);
                    atomicAdd(&hist[dst[e0 + j] >> 8], 1u);
                }
        }
    }
    __syncthreads();
    for (int b = threadIdx.x; b < NB; b += 256)
        gHist[(size_t)b * NC + blockIdx.x] = hist[b];
}

__global__ __launch_bounds__(256) void make_norm_src(const unsigned int* __restrict__ cnt4s,
                                                     float* __restrict__ norm_src, int N) {
    int i = blockIdx.x * 256 + threadIdx.x;
    if (i < N) {
        float od = (float)(cnt4s[i] + cnt4s[N + i] + cnt4s[2 * N + i] + cnt4s[3 * N + i]);
        norm_src[i] = rsqrtf(od > 1.f ? od : 1.f);
    }
}

// ---- Wt = fp16(W^T) for both layers ----
__global__ __launch_bounds__(256) void prep_w(const float* __restrict__ W1,
                                              const float* __restrict__ W2,
                                              _Float16* __restrict__ Wt) {
    const float* W = blockIdx.x ? W2 : W1;
    _Float16* T = Wt + (size_t)blockIdx.x * HD * HD;
    for (int i = threadIdx.x; i < HD * HD; i += 256) {
        int k = i >> 7, c = i & 127;
        T[c * HD + k] = (_Float16)W[i];
    }
}

// ---- 3-phase exclusive scan (generic length) ----
__global__ __launch_bounds__(256) void scan_a(const unsigned int* __restrict__ cnt,
                                              unsigned int* __restrict__ excl,
                                              unsigned int* __restrict__ bsum, int n) {
    int i = blockIdx.x * 256 + threadIdx.x;
    unsigned int v = (i < n) ? cnt[i] : 0u;
    unsigned int x = v;
#pragma unroll
    for (int d = 1; d < 64; d <<= 1) {
        unsigned int y = __shfl_up(x, d, 64);
        if ((threadIdx.x & 63) >= d) x += y;
    }
    __shared__ unsigned int wsum[4];
    if ((threadIdx.x & 63) == 63) wsum[threadIdx.x >> 6] = x;
    __syncthreads();
    unsigned int woff = 0;
    for (int w = 0; w < (int)(threadIdx.x >> 6); ++w) woff += wsum[w];
    unsigned int incl = x + woff;
    if (i < n) excl[i] = incl - v;
    if (threadIdx.x == 255) bsum[blockIdx.x] = incl;
}

__global__ __launch_bounds__(1024) void scan_b(const unsigned int* __restrict__ bsum,
                                               unsigned int* __restrict__ boff, int nb) {
    int t = threadIdx.x;
    unsigned int v = (t < nb) ? bsum[t] : 0u;
    unsigned int x = v;
#pragma unroll
    for (int d = 1; d < 64; d <<= 1) {
        unsigned int y = __shfl_up(x, d, 64);
        if ((t & 63) >= d) x += y;
    }
    __shared__ unsigned int wsum[16];
    if ((t & 63) == 63) wsum[t >> 6] = x;
    __syncthreads();
    unsigned int woff = 0;
    for (int w = 0; w < (t >> 6); ++w) woff += wsum[w];
    unsigned int incl = x + woff;
    if (t < nb) boff[t] = incl - v;
}

__global__ __launch_bounds__(256) void scan_c(unsigned int* __restrict__ excl,
                                              const unsigned int* __restrict__ boff, int n) {
    int i = blockIdx.x * 256 + threadIdx.x;
    if (i < n) excl[i] += boff[blockIdx.x];
}

// ---- coarse scatter: pack (dst&255)<<24 | src into bucket-contiguous runs ----
__global__ __launch_bounds__(256) void scatter_coarse(const int* __restrict__ src,
                                                      const int* __restrict__ dst,
                                                      const unsigned int* __restrict__ scanA,
                                                      unsigned int* __restrict__ packed,
                                                      int NB, int NC, int E) {
    __shared__ unsigned int curs[MAXNB];
    int chunk = blockIdx.x;
    for (int b = threadIdx.x; b < NB; b += 256)
        curs[b] = scanA[(size_t)b * NC + chunk];
    __syncthreads();
    int base = chunk * CHUNK;
    int end = base + CHUNK < E ? base + CHUNK : E;
    for (int e = base + threadIdx.x; e < end; e += 256) {
        int d = dst[e];
        int s = src[e];
        unsigned int pos = atomicAdd(&curs[d >> 8], 1u);
        packed[pos] = ((unsigned int)(d & 255) << 24) | (unsigned int)s;
    }
}

// ---- fine sort within each bucket + emit offsets/cnt/norm_dst ----
__global__ __launch_bounds__(256) void fine_sort(const unsigned int* __restrict__ packed,
                                                 const unsigned int* __restrict__ scanA,
                                                 int* __restrict__ sorted_src,
                                                 unsigned int* __restrict__ offsets,
                                                 unsigned int* __restrict__ cntg,
                                                 float* __restrict__ normd,
                                                 int NB, int NC, int N, int E) {
    __shared__ unsigned int cnt[256];
    __shared__ unsigned int curs[256];
    __shared__ unsigned int wsum[4];
    int b = blockIdx.x;
    int t = threadIdx.x;
    unsigned int S = scanA[(size_t)b * NC];
    unsigned int T = (b + 1 < NB) ? scanA[(size_t)(b + 1) * NC] : (unsigned int)E;
    cnt[t] = 0;
    __syncthreads();
    for (unsigned int j = S + t; j < T; j += 256)
        atomicAdd(&cnt[packed[j] >> 24], 1u);
    __syncthreads();
    unsigned int v = cnt[t], x = v;
    int lane = t & 63;
#pragma unroll
    for (int d = 1; d < 64; d <<= 1) {
        unsigned int y = __shfl_up(x, d, 64);
        if (lane >= d) x += y;
    }
    if (lane == 63) wsum[t >> 6] = x;
    __syncthreads();
    unsigned int woff = 0;
    for (int w = 0; w < (t >> 6); ++w) woff += wsum[w];
    unsigned int ex = x - v + woff;
    curs[t] = ex;
    int node = b * 256 + t;
    if (node < N) {
        offsets[node] = S + ex;
        cntg[node] = v;
        float f = (float)v;
        normd[node] = rsqrtf(f > 1.f ? f : 1.f);
    }
    __syncthreads();
    for (unsigned int j = S + t; j < T; j += 256) {
        unsigned int p = packed[j];
        unsigned int pos = S + atomicAdd(&curs[p >> 24], 1u);
        sorted_src[pos] = (int)(p & 0xFFFFFFu);
    }
}

// ---- xh = fp16(x * norm_src) ----
__global__ __launch_bounds__(256) void prep_x(const float* __restrict__ x,
                                              const float* __restrict__ norm,
                                              _Float16* __restrict__ xh, int total) {
    int t = blockIdx.x * 256 + threadIdx.x;   // one float4 per thread
    if (t >= total) return;
    int row = t >> 5;
    float nr = norm[row];
    float4 v = ((const float4*)x)[t];
    __half2 lo = __floats2half2_rn(v.x * nr, v.y * nr);
    __half2 hi = __floats2half2_rn(v.z * nr, v.w * nr);
    uint2 pk;
    pk.x = *(unsigned int*)&lo;
    pk.y = *(unsigned int*)&hi;
    ((uint2*)xh)[t] = pk;
}

// ---- h = xh @ W via MFMA, h stored SLICE-MAJOR: h[s][m][16] (s = col/16) ----
// Block 256 = 4 waves; wave w covers rows row0+w*16..+15 (all 128 cols). No LDS.
__global__ __launch_bounds__(256) void gemm_mfma(const _Float16* __restrict__ xh,
                                                 const _Float16* __restrict__ Wt,
                                                 _Float16* __restrict__ h, int NP, int n) {
    const int tid = threadIdx.x;
    const int w  = tid >> 6;
    const int l  = tid & 63;
    const int lg = l >> 4;    // lane group 0..3 -> k-chunk (lg*8)
    const int li = l & 15;
    const int m  = blockIdx.x * 64 + w * 16 + li;   // x row / output row

    // B-fragments: xh[m][kk*32 + lg*8 .. +7]
    const _Float16* xrow = xh + (size_t)m * HD + lg * 8;
    f16x8 xf[4];
#pragma unroll
    for (int kk = 0; kk < 4; ++kk)
        xf[kk] = *(const f16x8*)(xrow + kk * 32);

    f32x4 acc[8];
#pragma unroll
    for (int t = 0; t < 8; ++t) acc[t] = (f32x4){0.f, 0.f, 0.f, 0.f};

#pragma unroll
    for (int t = 0; t < 8; ++t) {
        const _Float16* wrow = Wt + (size_t)(t * 16 + li) * HD + lg * 8;
#pragma unroll
        for (int kk = 0; kk < 4; ++kk) {
            f16x8 wf = *(const f16x8*)(wrow + kk * 32);
            acc[t] = __builtin_amdgcn_mfma_f32_16x16x32_f16(wf, xf[kk], acc[t], 0, 0, 0);
        }
    }

    if (m < n) {
        // lane holds h[m][t*16 + lg*4 + r]; slice s = t; in-slice col = lg*4+r
#pragma unroll
        for (int t = 0; t < 8; ++t) {
            __half2 p0 = __floats2half2_rn(acc[t][0], acc[t][1]);
            __half2 p1 = __floats2half2_rn(acc[t][2], acc[t][3]);
            uint2 pk;
            pk.x = *(unsigned int*)&p0;
            pk.y = *(unsigned int*)&p1;
            *(uint2*)(h + ((size_t)t * NP + m) * 16 + lg * 4) = pk;
        }
    }
}

// ---- slice aggregation: 1 lane = 1 node x (block slice); fp16 pk accumulation ----
// h slice-major [8][NP][16]. slice = blockIdx%8 -> XCD-pinned (3.2MB, L2-resident).
template <bool MID>
__global__ __launch_bounds__(256) void aggregate_slice(const _Float16* __restrict__ h,
                                                       const int* __restrict__ sorted_src,
                                                       const unsigned int* __restrict__ offsets,
                                                       const unsigned int* __restrict__ cnt,
                                                       const float* __restrict__ norm_dst,
                                                       const float* __restrict__ nsrc,
                                                       const float* __restrict__ bias,
                                                       float* __restrict__ outF,
                                                       _Float16* __restrict__ outH,
                                                       int NP, int n) {
    const int slice = blockIdx.x & 7;
    const int node  = (blockIdx.x >> 3) * 256 + threadIdx.x;
    if (node >= n) return;

    const _Float16* hs = h + (size_t)slice * NP * 16;
    unsigned int off = offsets[node];
    unsigned int deg = cnt[node];
    const int* sp = sorted_src + off;

    f16x8 a0 = {}, a1 = {}, b0 = {}, b1 = {};
    unsigned int i = 0;
    for (; i + 2 <= deg; i += 2) {
        int s0 = sp[i];
        int s1 = sp[i + 1];
        const f16x8* r0 = (const f16x8*)(hs + (size_t)s0 * 16);
        const f16x8* r1 = (const f16x8*)(hs + (size_t)s1 * 16);
        a0 += r0[0];
        a1 += r0[1];
        b0 += r1[0];
        b1 += r1[1];
    }
    if (i < deg) {
        int s = sp[i];
        const f16x8* r = (const f16x8*)(hs + (size_t)s * 16);
        a0 += r[0];
        a1 += r[1];
    }
    a0 += b0;
    a1 += b1;

    float nd = norm_dst[node];
    const float* bp = bias + slice * 16;
    float f[16];
#pragma unroll
    for (int j = 0; j < 8; ++j) {
        f[j]     = fmaxf(fmaf((float)a0[j], nd, bp[j]), 0.f);
        f[8 + j] = fmaxf(fmaf((float)a1[j], nd, bp[8 + j]), 0.f);
    }
    if (MID) {
        float ns = nsrc[node];
        f16x8 w0, w1;
#pragma unroll
        for (int j = 0; j < 8; ++j) {
            w0[j] = (_Float16)(f[j] * ns);
            w1[j] = (_Float16)(f[8 + j] * ns);
        }
        _Float16* op = outH + (size_t)node * HD + slice * 16;
        *(f16x8*)op = w0;
        *(f16x8*)(op + 8) = w1;
    } else {
        float* op = outF + (size_t)node * HD + slice * 16;
#pragma unroll
        for (int q = 0; q < 4; ++q)
            *(float4*)(op + q * 4) = make_float4(f[q * 4], f[q * 4 + 1], f[q * 4 + 2], f[q * 4 + 3]);
    }
}

extern "C" void kernel_launch(void* const* d_in, const int* in_sizes, int n_in,
                              void* d_out, int out_size, void* d_ws, size_t ws_size,
                              hipStream_t stream) {
    const float* x   = (const float*)d_in[0];
    const float* W1  = (const float*)d_in[1];
    const float* b1  = (const float*)d_in[2];
    const float* W2  = (const float*)d_in[3];
    const float* b2  = (const float*)d_in[4];
    const int*   src = (const int*)d_in[5];
    const int*   dst = (const int*)d_in[6];

    const int N = in_sizes[0] / HD;
    const int E = in_sizes[5];
    float* out = (float*)d_out;

    const int NP = (N + 63) & ~63;               // padded rows for gemm/slice tiles
    const int NB = (N + 255) / 256;              // coarse buckets
    const int NC = (E + CHUNK - 1) / CHUNK;      // chunks
    const int scanLen = NB * NC;
    const int nbS = (scanLen + 255) / 256;       // <=1024
    const int nbN = (N + 255) / 256;
    const int aggGrid = 8 * ((N + 255) / 256);   // slice-major aggregate grid

    // workspace layout (4B units)
    float*        norm_src = (float*)d_ws;                    // N
    float*        normd    = norm_src + N;                    // N
    unsigned int* cntg     = (unsigned int*)(normd + N);      // N
    unsigned int* offsets  = cntg + N;                        // N
    unsigned int* cnt4s    = offsets + N;                     // 4N (zeroed)
    unsigned int* gHist    = cnt4s + 4 * N;                   // scanLen
    unsigned int* scanA    = gHist + scanLen;                 // scanLen
    unsigned int* bsum     = scanA + scanLen;                 // 1024
    unsigned int* boff     = bsum + 1024;                     // 1024
    unsigned int* packed   = boff + 1024;                     // E
    int*          sorted   = (int*)(packed + E);              // E
    _Float16*     h        = (_Float16*)(sorted + E);         // NP*HD fp16 (slice-major)
    _Float16*     xh       = h + (size_t)NP * HD;             // NP*HD fp16 (row-major)
    _Float16*     Wt       = xh + (size_t)NP * HD;            // 2*HD*HD fp16

    // ---- norms + weight transpose + bucket sort (shared by both layers) ----
    hipMemsetAsync(cnt4s, 0, (size_t)4 * N * 4, stream);
    prep_w<<<2, 256, 0, stream>>>(W1, W2, Wt);
    hist_count<<<NC, 256, 0, stream>>>(src, dst, cnt4s, gHist, N, NB, NC, E);
    make_norm_src<<<nbN, 256, 0, stream>>>(cnt4s, norm_src, N);
    scan_a<<<nbS, 256, 0, stream>>>(gHist, scanA, bsum, scanLen);
    scan_b<<<1, 1024, 0, stream>>>(bsum, boff, nbS);
    scan_c<<<nbS, 256, 0, stream>>>(scanA, boff, scanLen);
    scatter_coarse<<<NC, 256, 0, stream>>>(src, dst, scanA, packed, NB, NC, E);
    fine_sort<<<NB, 256, 0, stream>>>(packed, scanA, sorted, offsets, cntg, normd, NB, NC, N, E);

    // ---- layer 1 ----
    prep_x<<<(N * 32 + 255) / 256, 256, 0, stream>>>(x, norm_src, xh, N * 32);
    gemm_mfma<<<NP / 64, 256, 0, stream>>>(xh, Wt, h, NP, N);
    aggregate_slice<true><<<aggGrid, 256, 0, stream>>>(h, sorted, offsets, cntg, normd,
                                                       norm_src, b1, nullptr, xh, NP, N);

    // ---- layer 2 ----
    gemm_mfma<<<NP / 64, 256, 0, stream>>>(xh, Wt + HD * HD, h, NP, N);
    aggregate_slice<false><<<aggGrid, 256, 0, stream>>>(h, sorted, offsets, cntg, normd,
                                                        nullptr, b2, out, nullptr, NP, N);
}

// Round 9
// 351.961 us; speedup vs baseline: 1.4110x; 1.4110x over previous
//
#include <hip/hip_runtime.h>
#include <hip/hip_fp16.h>

#define HD 128      // hidden dim
#define CHUNK 8192  // edges per coarse-sort block
#define MAXNB 512   // max coarse buckets (N/256; N=100K -> 391)

typedef _Float16 f16x8 __attribute__((ext_vector_type(8)));
typedef float f32x4 __attribute__((ext_vector_type(4)));

// ---- coarse histogram of dst>>8 (pure LDS, no global atomics) ----
__global__ __launch_bounds__(256) void hist_coarse(const int* __restrict__ dst,
                                                   unsigned int* __restrict__ gHist,
                                                   int NB, int NC, int E) {
    __shared__ unsigned int hist[MAXNB];
    for (int b = threadIdx.x; b < NB; b += 256) hist[b] = 0;
    __syncthreads();
    int base = blockIdx.x * CHUNK;
    int e0 = base + 4 * threadIdx.x;
#pragma unroll
    for (int it = 0; it < CHUNK / 1024; ++it, e0 += 1024) {
        if (e0 + 3 < E) {
            int4 d4 = *(const int4*)(dst + e0);
            atomicAdd(&hist[d4.x >> 8], 1u);
            atomicAdd(&hist[d4.y >> 8], 1u);
            atomicAdd(&hist[d4.z >> 8], 1u);
            atomicAdd(&hist[d4.w >> 8], 1u);
        } else {
            for (int j = 0; j < 4; ++j)
                if (e0 + j < E) atomicAdd(&hist[dst[e0 + j] >> 8], 1u);
        }
    }
    __syncthreads();
    for (int b = threadIdx.x; b < NB; b += 256)
        gHist[(size_t)b * NC + blockIdx.x] = hist[b];
}

__global__ __launch_bounds__(256) void make_norm_src(const unsigned int* __restrict__ cnt4s,
                                                     float* __restrict__ norm_src, int N) {
    int i = blockIdx.x * 256 + threadIdx.x;
    if (i < N) {
        float od = (float)(cnt4s[i] + cnt4s[N + i] + cnt4s[2 * N + i] + cnt4s[3 * N + i]);
        norm_src[i] = rsqrtf(od > 1.f ? od : 1.f);
    }
}

// ---- Wt = fp16(W^T) for both layers ----
__global__ __launch_bounds__(256) void prep_w(const float* __restrict__ W1,
                                              const float* __restrict__ W2,
                                              _Float16* __restrict__ Wt) {
    const float* W = blockIdx.x ? W2 : W1;
    _Float16* T = Wt + (size_t)blockIdx.x * HD * HD;
    for (int i = threadIdx.x; i < HD * HD; i += 256) {
        int k = i >> 7, c = i & 127;
        T[c * HD + k] = (_Float16)W[i];
    }
}

// ---- 3-phase exclusive scan (generic length) ----
__global__ __launch_bounds__(256) void scan_a(const unsigned int* __restrict__ cnt,
                                              unsigned int* __restrict__ excl,
                                              unsigned int* __restrict__ bsum, int n) {
    int i = blockIdx.x * 256 + threadIdx.x;
    unsigned int v = (i < n) ? cnt[i] : 0u;
    unsigned int x = v;
#pragma unroll
    for (int d = 1; d < 64; d <<= 1) {
        unsigned int y = __shfl_up(x, d, 64);
        if ((threadIdx.x & 63) >= d) x += y;
    }
    __shared__ unsigned int wsum[4];
    if ((threadIdx.x & 63) == 63) wsum[threadIdx.x >> 6] = x;
    __syncthreads();
    unsigned int woff = 0;
    for (int w = 0; w < (int)(threadIdx.x >> 6); ++w) woff += wsum[w];
    unsigned int incl = x + woff;
    if (i < n) excl[i] = incl - v;
    if (threadIdx.x == 255) bsum[blockIdx.x] = incl;
}

__global__ __launch_bounds__(1024) void scan_b(const unsigned int* __restrict__ bsum,
                                               unsigned int* __restrict__ boff, int nb) {
    int t = threadIdx.x;
    unsigned int v = (t < nb) ? bsum[t] : 0u;
    unsigned int x = v;
#pragma unroll
    for (int d = 1; d < 64; d <<= 1) {
        unsigned int y = __shfl_up(x, d, 64);
        if ((t & 63) >= d) x += y;
    }
    __shared__ unsigned int wsum[16];
    if ((t & 63) == 63) wsum[t >> 6] = x;
    __syncthreads();
    unsigned int woff = 0;
    for (int w = 0; w < (t >> 6); ++w) woff += wsum[w];
    unsigned int incl = x + woff;
    if (t < nb) boff[t] = incl - v;
}

__global__ __launch_bounds__(256) void scan_c(unsigned int* __restrict__ excl,
                                              const unsigned int* __restrict__ boff, int n) {
    int i = blockIdx.x * 256 + threadIdx.x;
    if (i < n) excl[i] += boff[blockIdx.x];
}

// ---- coarse scatter (pack (dst&255)<<24|src) + fused src out-degree count ----
__global__ __launch_bounds__(256) void scatter_coarse(const int* __restrict__ src,
                                                      const int* __restrict__ dst,
                                                      const unsigned int* __restrict__ scanA,
                                                      unsigned int* __restrict__ packed,
                                                      unsigned int* __restrict__ cnt4s,
                                                      int N, int NB, int NC, int E) {
    __shared__ unsigned int curs[MAXNB];
    int chunk = blockIdx.x;
    for (int b = threadIdx.x; b < NB; b += 256)
        curs[b] = scanA[(size_t)b * NC + chunk];
    __syncthreads();
    int base = chunk * CHUNK;
    int e0 = base + 4 * threadIdx.x;
#pragma unroll
    for (int it = 0; it < CHUNK / 1024; ++it, e0 += 1024) {
        if (e0 + 3 < E) {
            int4 s4 = *(const int4*)(src + e0);
            int4 d4 = *(const int4*)(dst + e0);
            atomicAdd(&cnt4s[0 * N + s4.x], 1u);
            atomicAdd(&cnt4s[1 * N + s4.y], 1u);
            atomicAdd(&cnt4s[2 * N + s4.z], 1u);
            atomicAdd(&cnt4s[3 * N + s4.w], 1u);
            unsigned int p0 = atomicAdd(&curs[d4.x >> 8], 1u);
            unsigned int p1 = atomicAdd(&curs[d4.y >> 8], 1u);
            unsigned int p2 = atomicAdd(&curs[d4.z >> 8], 1u);
            unsigned int p3 = atomicAdd(&curs[d4.w >> 8], 1u);
            packed[p0] = ((unsigned int)(d4.x & 255) << 24) | (unsigned int)s4.x;
            packed[p1] = ((unsigned int)(d4.y & 255) << 24) | (unsigned int)s4.y;
            packed[p2] = ((unsigned int)(d4.z & 255) << 24) | (unsigned int)s4.z;
            packed[p3] = ((unsigned int)(d4.w & 255) << 24) | (unsigned int)s4.w;
        } else {
            for (int j = 0; j < 4; ++j)
                if (e0 + j < E) {
                    int d = dst[e0 + j], s = src[e0 + j];
                    atomicAdd(&cnt4s[j * N + s], 1u);
                    unsigned int pos = atomicAdd(&curs[d >> 8], 1u);
                    packed[pos] = ((unsigned int)(d & 255) << 24) | (unsigned int)s;
                }
        }
    }
}

// ---- fine sort within each bucket + emit offsets/cnt/norm_dst ----
__global__ __launch_bounds__(256) void fine_sort(const unsigned int* __restrict__ packed,
                                                 const unsigned int* __restrict__ scanA,
                                                 int* __restrict__ sorted_src,
                                                 unsigned int* __restrict__ offsets,
                                                 unsigned int* __restrict__ cntg,
                                                 float* __restrict__ normd,
                                                 int NB, int NC, int N, int E) {
    __shared__ unsigned int cnt[256];
    __shared__ unsigned int curs[256];
    __shared__ unsigned int wsum[4];
    int b = blockIdx.x;
    int t = threadIdx.x;
    unsigned int S = scanA[(size_t)b * NC];
    unsigned int T = (b + 1 < NB) ? scanA[(size_t)(b + 1) * NC] : (unsigned int)E;
    cnt[t] = 0;
    __syncthreads();
    for (unsigned int j = S + t; j < T; j += 256)
        atomicAdd(&cnt[packed[j] >> 24], 1u);
    __syncthreads();
    unsigned int v = cnt[t], x = v;
    int lane = t & 63;
#pragma unroll
    for (int d = 1; d < 64; d <<= 1) {
        unsigned int y = __shfl_up(x, d, 64);
        if (lane >= d) x += y;
    }
    if (lane == 63) wsum[t >> 6] = x;
    __syncthreads();
    unsigned int woff = 0;
    for (int w = 0; w < (t >> 6); ++w) woff += wsum[w];
    unsigned int ex = x - v + woff;
    curs[t] = ex;
    int node = b * 256 + t;
    if (node < N) {
        offsets[node] = S + ex;
        cntg[node] = v;
        float f = (float)v;
        normd[node] = rsqrtf(f > 1.f ? f : 1.f);
    }
    __syncthreads();
    for (unsigned int j = S + t; j < T; j += 256) {
        unsigned int p = packed[j];
        unsigned int pos = S + atomicAdd(&curs[p >> 24], 1u);
        sorted_src[pos] = (int)(p & 0xFFFFFFu);
    }
}

// ---- layer-1 GEMM: h = fp16((x*norm) @ W), f32 input, MFMA, no LDS ----
// Block 256 = 4 waves; wave w covers rows row0+w*16..+15.
__global__ __launch_bounds__(256) void gemm_mfma_f32(const float* __restrict__ x,
                                                     const float* __restrict__ norm,
                                                     const _Float16* __restrict__ Wt,
                                                     _Float16* __restrict__ h, int n) {
    const int tid = threadIdx.x;
    const int w  = tid >> 6;
    const int l  = tid & 63;
    const int lg = l >> 4;    // lane group 0..3 -> k-chunk (lg*8)
    const int li = l & 15;
    const int m  = blockIdx.x * 64 + w * 16 + li;

    f16x8 xf[4];
    if (m < n) {
        float nr = norm[m];
        const float* xrow = x + (size_t)m * HD + lg * 8;
#pragma unroll
        for (int kk = 0; kk < 4; ++kk) {
            float4 a = *(const float4*)(xrow + kk * 32);
            float4 b = *(const float4*)(xrow + kk * 32 + 4);
            f16x8 v;
            v[0] = (_Float16)(a.x * nr); v[1] = (_Float16)(a.y * nr);
            v[2] = (_Float16)(a.z * nr); v[3] = (_Float16)(a.w * nr);
            v[4] = (_Float16)(b.x * nr); v[5] = (_Float16)(b.y * nr);
            v[6] = (_Float16)(b.z * nr); v[7] = (_Float16)(b.w * nr);
            xf[kk] = v;
        }
    } else {
#pragma unroll
        for (int kk = 0; kk < 4; ++kk) xf[kk] = (f16x8){};
    }

    f32x4 acc[8];
#pragma unroll
    for (int t = 0; t < 8; ++t) acc[t] = (f32x4){0.f, 0.f, 0.f, 0.f};

#pragma unroll
    for (int t = 0; t < 8; ++t) {
        const _Float16* wrow = Wt + (size_t)(t * 16 + li) * HD + lg * 8;
#pragma unroll
        for (int kk = 0; kk < 4; ++kk) {
            f16x8 wf = *(const f16x8*)(wrow + kk * 32);
            acc[t] = __builtin_amdgcn_mfma_f32_16x16x32_f16(wf, xf[kk], acc[t], 0, 0, 0);
        }
    }

    if (m < n) {
        _Float16* hp = h + (size_t)m * HD + lg * 4;
#pragma unroll
        for (int t = 0; t < 8; ++t) {
            __half2 p0 = __floats2half2_rn(acc[t][0], acc[t][1]);
            __half2 p1 = __floats2half2_rn(acc[t][2], acc[t][3]);
            uint2 pk;
            pk.x = *(unsigned int*)&p0;
            pk.y = *(unsigned int*)&p1;
            *(uint2*)(hp + t * 16) = pk;
        }
    }
}

// ---- layer-2 GEMM: h = xh @ W, fp16 in, MFMA, no LDS ----
__global__ __launch_bounds__(256) void gemm_mfma(const _Float16* __restrict__ xh,
                                                 const _Float16* __restrict__ Wt,
                                                 _Float16* __restrict__ h, int n) {
    const int tid = threadIdx.x;
    const int w  = tid >> 6;
    const int l  = tid & 63;
    const int lg = l >> 4;
    const int li = l & 15;
    const int m  = blockIdx.x * 64 + w * 16 + li;

    const _Float16* xrow = xh + (size_t)m * HD + lg * 8;
    f16x8 xf[4];
#pragma unroll
    for (int kk = 0; kk < 4; ++kk)
        xf[kk] = *(const f16x8*)(xrow + kk * 32);

    f32x4 acc[8];
#pragma unroll
    for (int t = 0; t < 8; ++t) acc[t] = (f32x4){0.f, 0.f, 0.f, 0.f};

#pragma unroll
    for (int t = 0; t < 8; ++t) {
        const _Float16* wrow = Wt + (size_t)(t * 16 + li) * HD + lg * 8;
#pragma unroll
        for (int kk = 0; kk < 4; ++kk) {
            f16x8 wf = *(const f16x8*)(wrow + kk * 32);
            acc[t] = __builtin_amdgcn_mfma_f32_16x16x32_f16(wf, xf[kk], acc[t], 0, 0, 0);
        }
    }

    if (m < n) {
        _Float16* hp = h + (size_t)m * HD + lg * 4;
#pragma unroll
        for (int t = 0; t < 8; ++t) {
            __half2 p0 = __floats2half2_rn(acc[t][0], acc[t][1]);
            __half2 p1 = __floats2half2_rn(acc[t][2], acc[t][3]);
            uint2 pk;
            pk.x = *(unsigned int*)&p0;
            pk.y = *(unsigned int*)&p1;
            *(uint2*)(hp + t * 16) = pk;
        }
    }
}

// ---- fused gather-aggregate: wave/node, 4 edges/round x 16B/lane, 16-edge unroll ----
template <bool MID>
__global__ __launch_bounds__(256) void aggregate_k(const __half* __restrict__ h,
                                                   const int* __restrict__ sorted_src,
                                                   const unsigned int* __restrict__ offsets,
                                                   const unsigned int* __restrict__ cnt,
                                                   const float* __restrict__ norm_dst,
                                                   const float* __restrict__ nsrc,
                                                   const float* __restrict__ bias,
                                                   float* __restrict__ outF,
                                                   __half* __restrict__ outH, int n) {
    int node = blockIdx.x * 4 + (int)(threadIdx.x >> 6);
    if (node >= n) return;
    int lane = threadIdx.x & 63;
    int g   = lane >> 4;    // edge slot 0..3
    int sub = lane & 15;    // 16B slice of the 256B row

    unsigned int start = offsets[node];
    unsigned int deg   = cnt[node];
    const int* sp = sorted_src + start;
    const uint4* h4 = (const uint4*)h;

    float acc[8];
#pragma unroll
    for (int j = 0; j < 8; ++j) acc[j] = 0.f;

#define ACCUM(u)                                                                  \
    { float2 f;                                                                   \
      f = __half22float2(*(const __half2*)&(u).x); acc[0] += f.x; acc[1] += f.y;  \
      f = __half22float2(*(const __half2*)&(u).y); acc[2] += f.x; acc[3] += f.y;  \
      f = __half22float2(*(const __half2*)&(u).z); acc[4] += f.x; acc[5] += f.y;  \
      f = __half22float2(*(const __half2*)&(u).w); acc[6] += f.x; acc[7] += f.y; }

    unsigned int i = 0;
    for (; i + 16 <= deg; i += 16) {
        int s0 = sp[i + g];
        int s1 = sp[i + 4 + g];
        int s2 = sp[i + 8 + g];
        int s3 = sp[i + 12 + g];
        uint4 u0 = h4[(size_t)s0 * 16 + sub];
        uint4 u1 = h4[(size_t)s1 * 16 + sub];
        uint4 u2 = h4[(size_t)s2 * 16 + sub];
        uint4 u3 = h4[(size_t)s3 * 16 + sub];
        ACCUM(u0);
        ACCUM(u1);
        ACCUM(u2);
        ACCUM(u3);
    }
    for (; i < deg; i += 4) {
        if (i + g < deg) {
            int s = sp[i + g];
            uint4 u = h4[(size_t)s * 16 + sub];
            ACCUM(u);
        }
    }
#undef ACCUM

#pragma unroll
    for (int j = 0; j < 8; ++j) {
        acc[j] += __shfl_xor(acc[j], 16, 64);
        acc[j] += __shfl_xor(acc[j], 32, 64);
    }

    float nd = norm_dst[node];
    int col2 = sub * 4 + g;   // float2 / half2 column index 0..63
    float2 bb = ((const float2*)bias)[col2];
    float vx = fmaxf(fmaf(acc[g * 2 + 0], nd, bb.x), 0.f);
    float vy = fmaxf(fmaf(acc[g * 2 + 1], nd, bb.y), 0.f);
    if (MID) {
        float ns = nsrc[node];
        __half2 p = __floats2half2_rn(vx * ns, vy * ns);
        ((__half2*)outH)[(size_t)node * 64 + col2] = p;
    } else {
        ((float2*)outF)[(size_t)node * 64 + col2] = make_float2(vx, vy);
    }
}

extern "C" void kernel_launch(void* const* d_in, const int* in_sizes, int n_in,
                              void* d_out, int out_size, void* d_ws, size_t ws_size,
                              hipStream_t stream) {
    const float* x   = (const float*)d_in[0];
    const float* W1  = (const float*)d_in[1];
    const float* b1  = (const float*)d_in[2];
    const float* W2  = (const float*)d_in[3];
    const float* b2  = (const float*)d_in[4];
    const int*   src = (const int*)d_in[5];
    const int*   dst = (const int*)d_in[6];

    const int N = in_sizes[0] / HD;
    const int E = in_sizes[5];
    float* out = (float*)d_out;

    const int NP = (N + 63) & ~63;               // padded rows for gemm tiles
    const int NB = (N + 255) / 256;              // coarse buckets (391)
    const int NC = (E + CHUNK - 1) / CHUNK;      // chunks (196)
    const int scanLen = NB * NC;                 // ~77K
    const int nbS = (scanLen + 255) / 256;       // <=1024
    const int nbN = (N + 255) / 256;

    // workspace layout (4B units)
    float*        norm_src = (float*)d_ws;                    // N
    float*        normd    = norm_src + N;                    // N
    unsigned int* cntg     = (unsigned int*)(normd + N);      // N
    unsigned int* offsets  = cntg + N;                        // N
    unsigned int* cnt4s    = offsets + N;                     // 4N (zeroed)
    unsigned int* gHist    = cnt4s + 4 * N;                   // scanLen
    unsigned int* scanA    = gHist + scanLen;                 // scanLen
    unsigned int* bsum     = scanA + scanLen;                 // 1024
    unsigned int* boff     = bsum + 1024;                     // 1024
    unsigned int* packed   = boff + 1024;                     // E
    int*          sorted   = (int*)(packed + E);              // E
    _Float16*     h        = (_Float16*)(sorted + E);         // NP*HD fp16
    _Float16*     xh       = h + (size_t)NP * HD;             // NP*HD fp16
    _Float16*     Wt       = xh + (size_t)NP * HD;            // 2*HD*HD fp16

    // ---- norms + weight transpose + bucket sort (shared by both layers) ----
    hipMemsetAsync(cnt4s, 0, (size_t)4 * N * 4, stream);
    prep_w<<<2, 256, 0, stream>>>(W1, W2, Wt);
    hist_coarse<<<NC, 256, 0, stream>>>(dst, gHist, NB, NC, E);
    scan_a<<<nbS, 256, 0, stream>>>(gHist, scanA, bsum, scanLen);
    scan_b<<<1, 1024, 0, stream>>>(bsum, boff, nbS);
    scan_c<<<nbS, 256, 0, stream>>>(scanA, boff, scanLen);
    scatter_coarse<<<NC, 256, 0, stream>>>(src, dst, scanA, packed, cnt4s, N, NB, NC, E);
    make_norm_src<<<nbN, 256, 0, stream>>>(cnt4s, norm_src, N);
    fine_sort<<<NB, 256, 0, stream>>>(packed, scanA, sorted, offsets, cntg, normd, NB, NC, N, E);

    // ---- layer 1 (prep fused into gemm) ----
    gemm_mfma_f32<<<NP / 64, 256, 0, stream>>>(x, norm_src, Wt, h, N);
    aggregate_k<true><<<(N + 3) / 4, 256, 0, stream>>>((const __half*)h, sorted, offsets, cntg,
                                                       normd, norm_src, b1, nullptr,
                                                       (__half*)xh, N);

    // ---- layer 2 ----
    gemm_mfma<<<NP / 64, 256, 0, stream>>>(xh, Wt + HD * HD, h, N);
    aggregate_k<false><<<(N + 3) / 4, 256, 0, stream>>>((const __half*)h, sorted, offsets, cntg,
                                                        normd, nullptr, b2, out, nullptr, N);
}

// Round 10
// 343.191 us; speedup vs baseline: 1.4470x; 1.0256x over previous
//
#include <hip/hip_runtime.h>
#include <hip/hip_fp16.h>

#define HD 128      // hidden dim
#define CHUNK 8192  // edges per coarse-sort block
#define MAXNB 512   // max coarse buckets (N/256; N=100K -> 391)

typedef _Float16 f16x8 __attribute__((ext_vector_type(8)));
typedef float f32x4 __attribute__((ext_vector_type(4)));

// ---- coarse histogram of dst>>8 (blocks < NC) + fp16 W^T prep (last 2 blocks) ----
__global__ __launch_bounds__(256) void hist_prep(const int* __restrict__ dst,
                                                 unsigned int* __restrict__ gHist,
                                                 const float* __restrict__ W1,
                                                 const float* __restrict__ W2,
                                                 _Float16* __restrict__ Wt,
                                                 int NB, int NC, int E) {
    if ((int)blockIdx.x >= NC) {
        int which = blockIdx.x - NC;          // 0 -> W1, 1 -> W2
        const float* W = which ? W2 : W1;
        _Float16* T = Wt + (size_t)which * HD * HD;
        for (int i = threadIdx.x; i < HD * HD; i += 256) {
            int k = i >> 7, c = i & 127;
            T[c * HD + k] = (_Float16)W[i];
        }
        return;
    }
    __shared__ unsigned int hist[MAXNB];
    for (int b = threadIdx.x; b < NB; b += 256) hist[b] = 0;
    __syncthreads();
    int base = blockIdx.x * CHUNK;
    int e0 = base + 4 * threadIdx.x;
#pragma unroll
    for (int it = 0; it < CHUNK / 1024; ++it, e0 += 1024) {
        if (e0 + 3 < E) {
            int4 d4 = *(const int4*)(dst + e0);
            atomicAdd(&hist[d4.x >> 8], 1u);
            atomicAdd(&hist[d4.y >> 8], 1u);
            atomicAdd(&hist[d4.z >> 8], 1u);
            atomicAdd(&hist[d4.w >> 8], 1u);
        } else {
            for (int j = 0; j < 4; ++j)
                if (e0 + j < E) atomicAdd(&hist[dst[e0 + j] >> 8], 1u);
        }
    }
    __syncthreads();
    for (int b = threadIdx.x; b < NB; b += 256)
        gHist[(size_t)b * NC + blockIdx.x] = hist[b];
}

// ---- scan phase A: per-256-block exclusive scan + block sums ----
__global__ __launch_bounds__(256) void scan_a(const unsigned int* __restrict__ cnt,
                                              unsigned int* __restrict__ excl,
                                              unsigned int* __restrict__ bsum, int n) {
    int i = blockIdx.x * 256 + threadIdx.x;
    unsigned int v = (i < n) ? cnt[i] : 0u;
    unsigned int x = v;
#pragma unroll
    for (int d = 1; d < 64; d <<= 1) {
        unsigned int y = __shfl_up(x, d, 64);
        if ((threadIdx.x & 63) >= d) x += y;
    }
    __shared__ unsigned int wsum[4];
    if ((threadIdx.x & 63) == 63) wsum[threadIdx.x >> 6] = x;
    __syncthreads();
    unsigned int woff = 0;
    for (int w = 0; w < (int)(threadIdx.x >> 6); ++w) woff += wsum[w];
    unsigned int incl = x + woff;
    if (i < n) excl[i] = incl - v;
    if (threadIdx.x == 255) bsum[blockIdx.x] = incl;
}

// ---- scan phase B: single block scans the <=1024 block sums ----
__global__ __launch_bounds__(1024) void scan_b(const unsigned int* __restrict__ bsum,
                                               unsigned int* __restrict__ boff, int nb) {
    int t = threadIdx.x;
    unsigned int v = (t < nb) ? bsum[t] : 0u;
    unsigned int x = v;
#pragma unroll
    for (int d = 1; d < 64; d <<= 1) {
        unsigned int y = __shfl_up(x, d, 64);
        if ((t & 63) >= d) x += y;
    }
    __shared__ unsigned int wsum[16];
    if ((t & 63) == 63) wsum[t >> 6] = x;
    __syncthreads();
    unsigned int woff = 0;
    for (int w = 0; w < (t >> 6); ++w) woff += wsum[w];
    unsigned int incl = x + woff;
    if (t < nb) boff[t] = incl - v;
}

// ---- coarse scatter (pack (dst&255)<<24|src) + fused 8-replica src count ----
// scanA entries are phase-A partial scans; +boff[idx>>8] applied inline.
__global__ __launch_bounds__(256) void scatter_coarse(const int* __restrict__ src,
                                                      const int* __restrict__ dst,
                                                      const unsigned int* __restrict__ scanA,
                                                      const unsigned int* __restrict__ boff,
                                                      unsigned int* __restrict__ packed,
                                                      unsigned int* __restrict__ cnt8s,
                                                      int N, int NB, int NC, int E) {
    __shared__ unsigned int curs[MAXNB];
    int chunk = blockIdx.x;
    for (int b = threadIdx.x; b < NB; b += 256) {
        size_t idx = (size_t)b * NC + chunk;
        curs[b] = scanA[idx] + boff[idx >> 8];
    }
    __syncthreads();
    int base = chunk * CHUNK;
    int e0 = base + 4 * threadIdx.x;
    const int rb = (threadIdx.x & 1) << 2;   // replica bank 0 or 4
#pragma unroll
    for (int it = 0; it < CHUNK / 1024; ++it, e0 += 1024) {
        if (e0 + 3 < E) {
            int4 s4 = *(const int4*)(src + e0);
            int4 d4 = *(const int4*)(dst + e0);
            atomicAdd(&cnt8s[(size_t)(rb + 0) * N + s4.x], 1u);
            atomicAdd(&cnt8s[(size_t)(rb + 1) * N + s4.y], 1u);
            atomicAdd(&cnt8s[(size_t)(rb + 2) * N + s4.z], 1u);
            atomicAdd(&cnt8s[(size_t)(rb + 3) * N + s4.w], 1u);
            unsigned int p0 = atomicAdd(&curs[d4.x >> 8], 1u);
            unsigned int p1 = atomicAdd(&curs[d4.y >> 8], 1u);
            unsigned int p2 = atomicAdd(&curs[d4.z >> 8], 1u);
            unsigned int p3 = atomicAdd(&curs[d4.w >> 8], 1u);
            packed[p0] = ((unsigned int)(d4.x & 255) << 24) | (unsigned int)s4.x;
            packed[p1] = ((unsigned int)(d4.y & 255) << 24) | (unsigned int)s4.y;
            packed[p2] = ((unsigned int)(d4.z & 255) << 24) | (unsigned int)s4.z;
            packed[p3] = ((unsigned int)(d4.w & 255) << 24) | (unsigned int)s4.w;
        } else {
            for (int j = 0; j < 4; ++j)
                if (e0 + j < E) {
                    int d = dst[e0 + j], s = src[e0 + j];
                    atomicAdd(&cnt8s[(size_t)(rb + j) * N + s], 1u);
                    unsigned int pos = atomicAdd(&curs[d >> 8], 1u);
                    packed[pos] = ((unsigned int)(d & 255) << 24) | (unsigned int)s;
                }
        }
    }
}

// ---- fine sort within each bucket + emit offsets/cnt/norm_dst + norm_src ----
__global__ __launch_bounds__(256) void fine_sort(const unsigned int* __restrict__ packed,
                                                 const unsigned int* __restrict__ scanA,
                                                 const unsigned int* __restrict__ boff,
                                                 const unsigned int* __restrict__ cnt8s,
                                                 int* __restrict__ sorted_src,
                                                 unsigned int* __restrict__ offsets,
                                                 unsigned int* __restrict__ cntg,
                                                 float* __restrict__ normd,
                                                 float* __restrict__ norm_src,
                                                 int NB, int NC, int N, int E) {
    __shared__ unsigned int cnt[256];
    __shared__ unsigned int curs[256];
    __shared__ unsigned int wsum[4];
    int b = blockIdx.x;
    int t = threadIdx.x;
    size_t si = (size_t)b * NC;
    unsigned int S = scanA[si] + boff[si >> 8];
    unsigned int T;
    if (b + 1 < NB) {
        size_t ti = (size_t)(b + 1) * NC;
        T = scanA[ti] + boff[ti >> 8];
    } else {
        T = (unsigned int)E;
    }
    cnt[t] = 0;

    // fused norm_src: node = b*256 + t
    int node = b * 256 + t;
    if (node < N) {
        unsigned int od = 0;
#pragma unroll
        for (int r = 0; r < 8; ++r) od += cnt8s[(size_t)r * N + node];
        float f = (float)od;
        norm_src[node] = rsqrtf(f > 1.f ? f : 1.f);
    }
    __syncthreads();
    for (unsigned int j = S + t; j < T; j += 256)
        atomicAdd(&cnt[packed[j] >> 24], 1u);
    __syncthreads();
    unsigned int v = cnt[t], x = v;
    int lane = t & 63;
#pragma unroll
    for (int d = 1; d < 64; d <<= 1) {
        unsigned int y = __shfl_up(x, d, 64);
        if (lane >= d) x += y;
    }
    if (lane == 63) wsum[t >> 6] = x;
    __syncthreads();
    unsigned int woff = 0;
    for (int w = 0; w < (t >> 6); ++w) woff += wsum[w];
    unsigned int ex = x - v + woff;
    curs[t] = ex;
    if (node < N) {
        offsets[node] = S + ex;
        cntg[node] = v;
        float f = (float)v;
        normd[node] = rsqrtf(f > 1.f ? f : 1.f);
    }
    __syncthreads();
    for (unsigned int j = S + t; j < T; j += 256) {
        unsigned int p = packed[j];
        unsigned int pos = S + atomicAdd(&curs[p >> 24], 1u);
        sorted_src[pos] = (int)(p & 0xFFFFFFu);
    }
}

// ---- layer-1 GEMM: h = fp16((x*norm) @ W), f32 input, MFMA, no LDS ----
__global__ __launch_bounds__(256) void gemm_mfma_f32(const float* __restrict__ x,
                                                     const float* __restrict__ norm,
                                                     const _Float16* __restrict__ Wt,
                                                     _Float16* __restrict__ h, int n) {
    const int tid = threadIdx.x;
    const int w  = tid >> 6;
    const int l  = tid & 63;
    const int lg = l >> 4;    // lane group 0..3 -> k-chunk (lg*8)
    const int li = l & 15;
    const int m  = blockIdx.x * 64 + w * 16 + li;

    f16x8 xf[4];
    if (m < n) {
        float nr = norm[m];
        const float* xrow = x + (size_t)m * HD + lg * 8;
#pragma unroll
        for (int kk = 0; kk < 4; ++kk) {
            float4 a = *(const float4*)(xrow + kk * 32);
            float4 b = *(const float4*)(xrow + kk * 32 + 4);
            f16x8 v;
            v[0] = (_Float16)(a.x * nr); v[1] = (_Float16)(a.y * nr);
            v[2] = (_Float16)(a.z * nr); v[3] = (_Float16)(a.w * nr);
            v[4] = (_Float16)(b.x * nr); v[5] = (_Float16)(b.y * nr);
            v[6] = (_Float16)(b.z * nr); v[7] = (_Float16)(b.w * nr);
            xf[kk] = v;
        }
    } else {
#pragma unroll
        for (int kk = 0; kk < 4; ++kk) xf[kk] = (f16x8){};
    }

    f32x4 acc[8];
#pragma unroll
    for (int t = 0; t < 8; ++t) acc[t] = (f32x4){0.f, 0.f, 0.f, 0.f};

#pragma unroll
    for (int t = 0; t < 8; ++t) {
        const _Float16* wrow = Wt + (size_t)(t * 16 + li) * HD + lg * 8;
#pragma unroll
        for (int kk = 0; kk < 4; ++kk) {
            f16x8 wf = *(const f16x8*)(wrow + kk * 32);
            acc[t] = __builtin_amdgcn_mfma_f32_16x16x32_f16(wf, xf[kk], acc[t], 0, 0, 0);
        }
    }

    if (m < n) {
        _Float16* hp = h + (size_t)m * HD + lg * 4;
#pragma unroll
        for (int t = 0; t < 8; ++t) {
            __half2 p0 = __floats2half2_rn(acc[t][0], acc[t][1]);
            __half2 p1 = __floats2half2_rn(acc[t][2], acc[t][3]);
            uint2 pk;
            pk.x = *(unsigned int*)&p0;
            pk.y = *(unsigned int*)&p1;
            *(uint2*)(hp + t * 16) = pk;
        }
    }
}

// ---- layer-2 GEMM: h = xh @ W, fp16 in, MFMA, no LDS ----
__global__ __launch_bounds__(256) void gemm_mfma(const _Float16* __restrict__ xh,
                                                 const _Float16* __restrict__ Wt,
                                                 _Float16* __restrict__ h, int n) {
    const int tid = threadIdx.x;
    const int w  = tid >> 6;
    const int l  = tid & 63;
    const int lg = l >> 4;
    const int li = l & 15;
    const int m  = blockIdx.x * 64 + w * 16 + li;

    const _Float16* xrow = xh + (size_t)m * HD + lg * 8;
    f16x8 xf[4];
#pragma unroll
    for (int kk = 0; kk < 4; ++kk)
        xf[kk] = *(const f16x8*)(xrow + kk * 32);

    f32x4 acc[8];
#pragma unroll
    for (int t = 0; t < 8; ++t) acc[t] = (f32x4){0.f, 0.f, 0.f, 0.f};

#pragma unroll
    for (int t = 0; t < 8; ++t) {
        const _Float16* wrow = Wt + (size_t)(t * 16 + li) * HD + lg * 8;
#pragma unroll
        for (int kk = 0; kk < 4; ++kk) {
            f16x8 wf = *(const f16x8*)(wrow + kk * 32);
            acc[t] = __builtin_amdgcn_mfma_f32_16x16x32_f16(wf, xf[kk], acc[t], 0, 0, 0);
        }
    }

    if (m < n) {
        _Float16* hp = h + (size_t)m * HD + lg * 4;
#pragma unroll
        for (int t = 0; t < 8; ++t) {
            __half2 p0 = __floats2half2_rn(acc[t][0], acc[t][1]);
            __half2 p1 = __floats2half2_rn(acc[t][2], acc[t][3]);
            uint2 pk;
            pk.x = *(unsigned int*)&p0;
            pk.y = *(unsigned int*)&p1;
            *(uint2*)(hp + t * 16) = pk;
        }
    }
}

// ---- fused gather-aggregate: wave/node, 4 edges/round x 16B/lane, 16-edge unroll ----
template <bool MID>
__global__ __launch_bounds__(256) void aggregate_k(const __half* __restrict__ h,
                                                   const int* __restrict__ sorted_src,
                                                   const unsigned int* __restrict__ offsets,
                                                   const unsigned int* __restrict__ cnt,
                                                   const float* __restrict__ norm_dst,
                                                   const float* __restrict__ nsrc,
                                                   const float* __restrict__ bias,
                                                   float* __restrict__ outF,
                                                   __half* __restrict__ outH, int n) {
    int node = blockIdx.x * 4 + (int)(threadIdx.x >> 6);
    if (node >= n) return;
    int lane = threadIdx.x & 63;
    int g   = lane >> 4;    // edge slot 0..3
    int sub = lane & 15;    // 16B slice of the 256B row

    unsigned int start = offsets[node];
    unsigned int deg   = cnt[node];
    const int* sp = sorted_src + start;
    const uint4* h4 = (const uint4*)h;

    float acc[8];
#pragma unroll
    for (int j = 0; j < 8; ++j) acc[j] = 0.f;

#define ACCUM(u)                                                                  \
    { float2 f;                                                                   \
      f = __half22float2(*(const __half2*)&(u).x); acc[0] += f.x; acc[1] += f.y;  \
      f = __half22float2(*(const __half2*)&(u).y); acc[2] += f.x; acc[3] += f.y;  \
      f = __half22float2(*(const __half2*)&(u).z); acc[4] += f.x; acc[5] += f.y;  \
      f = __half22float2(*(const __half2*)&(u).w); acc[6] += f.x; acc[7] += f.y; }

    unsigned int i = 0;
    for (; i + 16 <= deg; i += 16) {
        int s0 = sp[i + g];
        int s1 = sp[i + 4 + g];
        int s2 = sp[i + 8 + g];
        int s3 = sp[i + 12 + g];
        uint4 u0 = h4[(size_t)s0 * 16 + sub];
        uint4 u1 = h4[(size_t)s1 * 16 + sub];
        uint4 u2 = h4[(size_t)s2 * 16 + sub];
        uint4 u3 = h4[(size_t)s3 * 16 + sub];
        ACCUM(u0);
        ACCUM(u1);
        ACCUM(u2);
        ACCUM(u3);
    }
    for (; i < deg; i += 4) {
        if (i + g < deg) {
            int s = sp[i + g];
            uint4 u = h4[(size_t)s * 16 + sub];
            ACCUM(u);
        }
    }
#undef ACCUM

#pragma unroll
    for (int j = 0; j < 8; ++j) {
        acc[j] += __shfl_xor(acc[j], 16, 64);
        acc[j] += __shfl_xor(acc[j], 32, 64);
    }

    float nd = norm_dst[node];
    int col2 = sub * 4 + g;   // float2 / half2 column index 0..63
    float2 bb = ((const float2*)bias)[col2];
    float vx = fmaxf(fmaf(acc[g * 2 + 0], nd, bb.x), 0.f);
    float vy = fmaxf(fmaf(acc[g * 2 + 1], nd, bb.y), 0.f);
    if (MID) {
        float ns = nsrc[node];
        __half2 p = __floats2half2_rn(vx * ns, vy * ns);
        ((__half2*)outH)[(size_t)node * 64 + col2] = p;
    } else {
        ((float2*)outF)[(size_t)node * 64 + col2] = make_float2(vx, vy);
    }
}

extern "C" void kernel_launch(void* const* d_in, const int* in_sizes, int n_in,
                              void* d_out, int out_size, void* d_ws, size_t ws_size,
                              hipStream_t stream) {
    const float* x   = (const float*)d_in[0];
    const float* W1  = (const float*)d_in[1];
    const float* b1  = (const float*)d_in[2];
    const float* W2  = (const float*)d_in[3];
    const float* b2  = (const float*)d_in[4];
    const int*   src = (const int*)d_in[5];
    const int*   dst = (const int*)d_in[6];

    const int N = in_sizes[0] / HD;
    const int E = in_sizes[5];
    float* out = (float*)d_out;

    const int NP = (N + 63) & ~63;               // padded rows for gemm tiles
    const int NB = (N + 255) / 256;              // coarse buckets (391)
    const int NC = (E + CHUNK - 1) / CHUNK;      // chunks (196)
    const int scanLen = NB * NC;                 // ~77K
    const int nbS = (scanLen + 255) / 256;       // <=1024

    // workspace layout (4B units)
    float*        norm_src = (float*)d_ws;                    // N
    float*        normd    = norm_src + N;                    // N
    unsigned int* cntg     = (unsigned int*)(normd + N);      // N
    unsigned int* offsets  = cntg + N;                        // N
    unsigned int* cnt8s    = offsets + N;                     // 8N (zeroed)
    unsigned int* gHist    = cnt8s + 8 * (size_t)N;           // scanLen
    unsigned int* scanA    = gHist + scanLen;                 // scanLen
    unsigned int* bsum     = scanA + scanLen;                 // 1024
    unsigned int* boff     = bsum + 1024;                     // 1024
    unsigned int* packed   = boff + 1024;                     // E
    int*          sorted   = (int*)(packed + E);              // E
    _Float16*     h        = (_Float16*)(sorted + E);         // NP*HD fp16
    _Float16*     xh       = h + (size_t)NP * HD;             // NP*HD fp16
    _Float16*     Wt       = xh + (size_t)NP * HD;            // 2*HD*HD fp16

    // ---- norms + weight transpose + bucket sort (shared by both layers) ----
    hipMemsetAsync(cnt8s, 0, (size_t)8 * N * 4, stream);
    hist_prep<<<NC + 2, 256, 0, stream>>>(dst, gHist, W1, W2, Wt, NB, NC, E);
    scan_a<<<nbS, 256, 0, stream>>>(gHist, scanA, bsum, scanLen);
    scan_b<<<1, 1024, 0, stream>>>(bsum, boff, nbS);
    scatter_coarse<<<NC, 256, 0, stream>>>(src, dst, scanA, boff, packed, cnt8s, N, NB, NC, E);
    fine_sort<<<NB, 256, 0, stream>>>(packed, scanA, boff, cnt8s, sorted, offsets, cntg,
                                      normd, norm_src, NB, NC, N, E);

    // ---- layer 1 (prep fused into gemm) ----
    gemm_mfma_f32<<<NP / 64, 256, 0, stream>>>(x, norm_src, Wt, h, N);
    aggregate_k<true><<<(N + 3) / 4, 256, 0, stream>>>((const __half*)h, sorted, offsets, cntg,
                                                       normd, norm_src, b1, nullptr,
                                                       (__half*)xh, N);

    // ---- layer 2 ----
    gemm_mfma<<<NP / 64, 256, 0, stream>>>(xh, Wt + HD * HD, h, N);
    aggregate_k<false><<<(N + 3) / 4, 256, 0, stream>>>((const __half*)h, sorted, offsets, cntg,
                                                        normd, nullptr, b2, out, nullptr, N);
}

// Round 11
// 342.578 us; speedup vs baseline: 1.4496x; 1.0018x over previous
//
#include <hip/hip_runtime.h>
#include <hip/hip_fp16.h>

#define HD 128      // hidden dim
#define CHUNK 8192  // edges per coarse-sort block
#define MAXNB 512   // max coarse buckets (N/256; N=100K -> 391)

typedef _Float16 f16x8 __attribute__((ext_vector_type(8)));
typedef float f32x4 __attribute__((ext_vector_type(4)));

// ---- coarse histogram of dst>>8 (blocks < NC) + fp16 W^T prep (last 2 blocks) ----
__global__ __launch_bounds__(512) void hist_prep(const int* __restrict__ dst,
                                                 unsigned int* __restrict__ gHist,
                                                 const float* __restrict__ W1,
                                                 const float* __restrict__ W2,
                                                 _Float16* __restrict__ Wt,
                                                 int NB, int NC, int E) {
    if ((int)blockIdx.x >= NC) {
        int which = blockIdx.x - NC;          // 0 -> W1, 1 -> W2
        const float* W = which ? W2 : W1;
        _Float16* T = Wt + (size_t)which * HD * HD;
        for (int i = threadIdx.x; i < HD * HD; i += 512) {
            int k = i >> 7, c = i & 127;
            T[c * HD + k] = (_Float16)W[i];
        }
        return;
    }
    __shared__ unsigned int hist[MAXNB];
    for (int b = threadIdx.x; b < NB; b += 512) hist[b] = 0;
    __syncthreads();
    int base = blockIdx.x * CHUNK;
    int e0 = base + 4 * threadIdx.x;
#pragma unroll
    for (int it = 0; it < CHUNK / 2048; ++it, e0 += 2048) {
        if (e0 + 3 < E) {
            int4 d4 = *(const int4*)(dst + e0);
            atomicAdd(&hist[d4.x >> 8], 1u);
            atomicAdd(&hist[d4.y >> 8], 1u);
            atomicAdd(&hist[d4.z >> 8], 1u);
            atomicAdd(&hist[d4.w >> 8], 1u);
        } else {
            for (int j = 0; j < 4; ++j)
                if (e0 + j < E) atomicAdd(&hist[dst[e0 + j] >> 8], 1u);
        }
    }
    __syncthreads();
    for (int b = threadIdx.x; b < NB; b += 512)
        gHist[(size_t)b * NC + blockIdx.x] = hist[b];
}

// ---- scan phase A: per-256-block exclusive scan + block sums ----
__global__ __launch_bounds__(256) void scan_a(const unsigned int* __restrict__ cnt,
                                              unsigned int* __restrict__ excl,
                                              unsigned int* __restrict__ bsum, int n) {
    int i = blockIdx.x * 256 + threadIdx.x;
    unsigned int v = (i < n) ? cnt[i] : 0u;
    unsigned int x = v;
#pragma unroll
    for (int d = 1; d < 64; d <<= 1) {
        unsigned int y = __shfl_up(x, d, 64);
        if ((threadIdx.x & 63) >= d) x += y;
    }
    __shared__ unsigned int wsum[4];
    if ((threadIdx.x & 63) == 63) wsum[threadIdx.x >> 6] = x;
    __syncthreads();
    unsigned int woff = 0;
    for (int w = 0; w < (int)(threadIdx.x >> 6); ++w) woff += wsum[w];
    unsigned int incl = x + woff;
    if (i < n) excl[i] = incl - v;
    if (threadIdx.x == 255) bsum[blockIdx.x] = incl;
}

// ---- scan phase B: single block scans the <=1024 block sums ----
__global__ __launch_bounds__(1024) void scan_b(const unsigned int* __restrict__ bsum,
                                               unsigned int* __restrict__ boff, int nb) {
    int t = threadIdx.x;
    unsigned int v = (t < nb) ? bsum[t] : 0u;
    unsigned int x = v;
#pragma unroll
    for (int d = 1; d < 64; d <<= 1) {
        unsigned int y = __shfl_up(x, d, 64);
        if ((t & 63) >= d) x += y;
    }
    __shared__ unsigned int wsum[16];
    if ((t & 63) == 63) wsum[t >> 6] = x;
    __syncthreads();
    unsigned int woff = 0;
    for (int w = 0; w < (t >> 6); ++w) woff += wsum[w];
    unsigned int incl = x + woff;
    if (t < nb) boff[t] = incl - v;
}

// ---- coarse scatter (pack (dst&255)<<24|src) + fused 8-replica src count ----
__global__ __launch_bounds__(512) void scatter_coarse(const int* __restrict__ src,
                                                      const int* __restrict__ dst,
                                                      const unsigned int* __restrict__ scanA,
                                                      const unsigned int* __restrict__ boff,
                                                      unsigned int* __restrict__ packed,
                                                      unsigned int* __restrict__ cnt8s,
                                                      int N, int NB, int NC, int E) {
    __shared__ unsigned int curs[MAXNB];
    int chunk = blockIdx.x;
    for (int b = threadIdx.x; b < NB; b += 512) {
        size_t idx = (size_t)b * NC + chunk;
        curs[b] = scanA[idx] + boff[idx >> 8];
    }
    __syncthreads();
    int base = chunk * CHUNK;
    int e0 = base + 4 * threadIdx.x;
    const int rb = (threadIdx.x & 1) << 2;   // replica bank 0 or 4
#pragma unroll
    for (int it = 0; it < CHUNK / 2048; ++it, e0 += 2048) {
        if (e0 + 3 < E) {
            int4 s4 = *(const int4*)(src + e0);
            int4 d4 = *(const int4*)(dst + e0);
            atomicAdd(&cnt8s[(size_t)(rb + 0) * N + s4.x], 1u);
            atomicAdd(&cnt8s[(size_t)(rb + 1) * N + s4.y], 1u);
            atomicAdd(&cnt8s[(size_t)(rb + 2) * N + s4.z], 1u);
            atomicAdd(&cnt8s[(size_t)(rb + 3) * N + s4.w], 1u);
            unsigned int p0 = atomicAdd(&curs[d4.x >> 8], 1u);
            unsigned int p1 = atomicAdd(&curs[d4.y >> 8], 1u);
            unsigned int p2 = atomicAdd(&curs[d4.z >> 8], 1u);
            unsigned int p3 = atomicAdd(&curs[d4.w >> 8], 1u);
            packed[p0] = ((unsigned int)(d4.x & 255) << 24) | (unsigned int)s4.x;
            packed[p1] = ((unsigned int)(d4.y & 255) << 24) | (unsigned int)s4.y;
            packed[p2] = ((unsigned int)(d4.z & 255) << 24) | (unsigned int)s4.z;
            packed[p3] = ((unsigned int)(d4.w & 255) << 24) | (unsigned int)s4.w;
        } else {
            for (int j = 0; j < 4; ++j)
                if (e0 + j < E) {
                    int d = dst[e0 + j], s = src[e0 + j];
                    atomicAdd(&cnt8s[(size_t)(rb + j) * N + s], 1u);
                    unsigned int pos = atomicAdd(&curs[d >> 8], 1u);
                    packed[pos] = ((unsigned int)(d & 255) << 24) | (unsigned int)s;
                }
        }
    }
}

// ---- fine sort within each bucket + emit offsets/cnt/norm_dst + norm_src ----
__global__ __launch_bounds__(256) void fine_sort(const unsigned int* __restrict__ packed,
                                                 const unsigned int* __restrict__ scanA,
                                                 const unsigned int* __restrict__ boff,
                                                 const unsigned int* __restrict__ cnt8s,
                                                 int* __restrict__ sorted_src,
                                                 unsigned int* __restrict__ offsets,
                                                 unsigned int* __restrict__ cntg,
                                                 float* __restrict__ normd,
                                                 float* __restrict__ norm_src,
                                                 int NB, int NC, int N, int E) {
    __shared__ unsigned int cnt[256];
    __shared__ unsigned int curs[256];
    __shared__ unsigned int wsum[4];
    int b = blockIdx.x;
    int t = threadIdx.x;
    size_t si = (size_t)b * NC;
    unsigned int S = scanA[si] + boff[si >> 8];
    unsigned int T;
    if (b + 1 < NB) {
        size_t ti = (size_t)(b + 1) * NC;
        T = scanA[ti] + boff[ti >> 8];
    } else {
        T = (unsigned int)E;
    }
    cnt[t] = 0;

    int node = b * 256 + t;
    if (node < N) {
        unsigned int od = 0;
#pragma unroll
        for (int r = 0; r < 8; ++r) od += cnt8s[(size_t)r * N + node];
        float f = (float)od;
        norm_src[node] = rsqrtf(f > 1.f ? f : 1.f);
    }
    __syncthreads();
    for (unsigned int j = S + t; j < T; j += 256)
        atomicAdd(&cnt[packed[j] >> 24], 1u);
    __syncthreads();
    unsigned int v = cnt[t], x = v;
    int lane = t & 63;
#pragma unroll
    for (int d = 1; d < 64; d <<= 1) {
        unsigned int y = __shfl_up(x, d, 64);
        if (lane >= d) x += y;
    }
    if (lane == 63) wsum[t >> 6] = x;
    __syncthreads();
    unsigned int woff = 0;
    for (int w = 0; w < (t >> 6); ++w) woff += wsum[w];
    unsigned int ex = x - v + woff;
    curs[t] = ex;
    if (node < N) {
        offsets[node] = S + ex;
        cntg[node] = v;
        float f = (float)v;
        normd[node] = rsqrtf(f > 1.f ? f : 1.f);
    }
    __syncthreads();
    for (unsigned int j = S + t; j < T; j += 256) {
        unsigned int p = packed[j];
        unsigned int pos = S + atomicAdd(&curs[p >> 24], 1u);
        sorted_src[pos] = (int)(p & 0xFFFFFFu);
    }
}

// ---- layer-1 GEMM: h = fp16((x*norm) @ W), f32 input, MFMA, no LDS ----
__global__ __launch_bounds__(256) void gemm_mfma_f32(const float* __restrict__ x,
                                                     const float* __restrict__ norm,
                                                     const _Float16* __restrict__ Wt,
                                                     _Float16* __restrict__ h, int n) {
    const int tid = threadIdx.x;
    const int w  = tid >> 6;
    const int l  = tid & 63;
    const int lg = l >> 4;    // lane group 0..3 -> k-chunk (lg*8)
    const int li = l & 15;
    const int m  = blockIdx.x * 64 + w * 16 + li;

    f16x8 xf[4];
    if (m < n) {
        float nr = norm[m];
        const float* xrow = x + (size_t)m * HD + lg * 8;
#pragma unroll
        for (int kk = 0; kk < 4; ++kk) {
            float4 a = *(const float4*)(xrow + kk * 32);
            float4 b = *(const float4*)(xrow + kk * 32 + 4);
            f16x8 v;
            v[0] = (_Float16)(a.x * nr); v[1] = (_Float16)(a.y * nr);
            v[2] = (_Float16)(a.z * nr); v[3] = (_Float16)(a.w * nr);
            v[4] = (_Float16)(b.x * nr); v[5] = (_Float16)(b.y * nr);
            v[6] = (_Float16)(b.z * nr); v[7] = (_Float16)(b.w * nr);
            xf[kk] = v;
        }
    } else {
#pragma unroll
        for (int kk = 0; kk < 4; ++kk) xf[kk] = (f16x8){};
    }

    f32x4 acc[8];
#pragma unroll
    for (int t = 0; t < 8; ++t) acc[t] = (f32x4){0.f, 0.f, 0.f, 0.f};

#pragma unroll
    for (int t = 0; t < 8; ++t) {
        const _Float16* wrow = Wt + (size_t)(t * 16 + li) * HD + lg * 8;
#pragma unroll
        for (int kk = 0; kk < 4; ++kk) {
            f16x8 wf = *(const f16x8*)(wrow + kk * 32);
            acc[t] = __builtin_amdgcn_mfma_f32_16x16x32_f16(wf, xf[kk], acc[t], 0, 0, 0);
        }
    }

    if (m < n) {
        _Float16* hp = h + (size_t)m * HD + lg * 4;
#pragma unroll
        for (int t = 0; t < 8; ++t) {
            __half2 p0 = __floats2half2_rn(acc[t][0], acc[t][1]);
            __half2 p1 = __floats2half2_rn(acc[t][2], acc[t][3]);
            uint2 pk;
            pk.x = *(unsigned int*)&p0;
            pk.y = *(unsigned int*)&p1;
            *(uint2*)(hp + t * 16) = pk;
        }
    }
}

// ---- layer-2 GEMM: h = xh @ W, fp16 in, MFMA, no LDS ----
__global__ __launch_bounds__(256) void gemm_mfma(const _Float16* __restrict__ xh,
                                                 const _Float16* __restrict__ Wt,
                                                 _Float16* __restrict__ h, int n) {
    const int tid = threadIdx.x;
    const int w  = tid >> 6;
    const int l  = tid & 63;
    const int lg = l >> 4;
    const int li = l & 15;
    const int m  = blockIdx.x * 64 + w * 16 + li;

    const _Float16* xrow = xh + (size_t)m * HD + lg * 8;
    f16x8 xf[4];
#pragma unroll
    for (int kk = 0; kk < 4; ++kk)
        xf[kk] = *(const f16x8*)(xrow + kk * 32);

    f32x4 acc[8];
#pragma unroll
    for (int t = 0; t < 8; ++t) acc[t] = (f32x4){0.f, 0.f, 0.f, 0.f};

#pragma unroll
    for (int t = 0; t < 8; ++t) {
        const _Float16* wrow = Wt + (size_t)(t * 16 + li) * HD + lg * 8;
#pragma unroll
        for (int kk = 0; kk < 4; ++kk) {
            f16x8 wf = *(const f16x8*)(wrow + kk * 32);
            acc[t] = __builtin_amdgcn_mfma_f32_16x16x32_f16(wf, xf[kk], acc[t], 0, 0, 0);
        }
    }

    if (m < n) {
        _Float16* hp = h + (size_t)m * HD + lg * 4;
#pragma unroll
        for (int t = 0; t < 8; ++t) {
            __half2 p0 = __floats2half2_rn(acc[t][0], acc[t][1]);
            __half2 p1 = __floats2half2_rn(acc[t][2], acc[t][3]);
            uint2 pk;
            pk.x = *(unsigned int*)&p0;
            pk.y = *(unsigned int*)&p1;
            *(uint2*)(hp + t * 16) = pk;
        }
    }
}

// ---- fused gather-aggregate: wave/node, 4 edges/round x 16B/lane ----
// fp16 packed accumulation (4 v_pk_add_f16 per 16B load), f32 only at epilogue.
template <bool MID>
__global__ __launch_bounds__(256) void aggregate_k(const __half* __restrict__ h,
                                                   const int* __restrict__ sorted_src,
                                                   const unsigned int* __restrict__ offsets,
                                                   const unsigned int* __restrict__ cnt,
                                                   const float* __restrict__ norm_dst,
                                                   const float* __restrict__ nsrc,
                                                   const float* __restrict__ bias,
                                                   float* __restrict__ outF,
                                                   __half* __restrict__ outH, int n) {
    int node = blockIdx.x * 4 + (int)(threadIdx.x >> 6);
    if (node >= n) return;
    int lane = threadIdx.x & 63;
    int g   = lane >> 4;    // edge slot 0..3
    int sub = lane & 15;    // 16B slice of the 256B row

    unsigned int start = offsets[node];
    unsigned int deg   = cnt[node];
    const int* sp = sorted_src + start;
    const uint4* h4 = (const uint4*)h;

    f16x8 hacc = {};
    unsigned int i = 0;
    for (; i + 16 <= deg; i += 16) {
        int s0 = sp[i + g];
        int s1 = sp[i + 4 + g];
        int s2 = sp[i + 8 + g];
        int s3 = sp[i + 12 + g];
        uint4 u0 = h4[(size_t)s0 * 16 + sub];
        uint4 u1 = h4[(size_t)s1 * 16 + sub];
        uint4 u2 = h4[(size_t)s2 * 16 + sub];
        uint4 u3 = h4[(size_t)s3 * 16 + sub];
        hacc += *(const f16x8*)&u0;
        hacc += *(const f16x8*)&u1;
        hacc += *(const f16x8*)&u2;
        hacc += *(const f16x8*)&u3;
    }
    for (; i < deg; i += 4) {
        if (i + g < deg) {
            int s = sp[i + g];
            uint4 u = h4[(size_t)s * 16 + sub];
            hacc += *(const f16x8*)&u;
        }
    }

    float acc[8];
#pragma unroll
    for (int j = 0; j < 8; ++j) acc[j] = (float)hacc[j];

#pragma unroll
    for (int j = 0; j < 8; ++j) {
        acc[j] += __shfl_xor(acc[j], 16, 64);
        acc[j] += __shfl_xor(acc[j], 32, 64);
    }

    float nd = norm_dst[node];
    int col2 = sub * 4 + g;   // float2 / half2 column index 0..63
    float2 bb = ((const float2*)bias)[col2];
    float vx = fmaxf(fmaf(acc[g * 2 + 0], nd, bb.x), 0.f);
    float vy = fmaxf(fmaf(acc[g * 2 + 1], nd, bb.y), 0.f);
    if (MID) {
        float ns = nsrc[node];
        __half2 p = __floats2half2_rn(vx * ns, vy * ns);
        ((__half2*)outH)[(size_t)node * 64 + col2] = p;
    } else {
        ((float2*)outF)[(size_t)node * 64 + col2] = make_float2(vx, vy);
    }
}

extern "C" void kernel_launch(void* const* d_in, const int* in_sizes, int n_in,
                              void* d_out, int out_size, void* d_ws, size_t ws_size,
                              hipStream_t stream) {
    const float* x   = (const float*)d_in[0];
    const float* W1  = (const float*)d_in[1];
    const float* b1  = (const float*)d_in[2];
    const float* W2  = (const float*)d_in[3];
    const float* b2  = (const float*)d_in[4];
    const int*   src = (const int*)d_in[5];
    const int*   dst = (const int*)d_in[6];

    const int N = in_sizes[0] / HD;
    const int E = in_sizes[5];
    float* out = (float*)d_out;

    const int NP = (N + 63) & ~63;               // padded rows for gemm tiles
    const int NB = (N + 255) / 256;              // coarse buckets (391)
    const int NC = (E + CHUNK - 1) / CHUNK;      // chunks (196)
    const int scanLen = NB * NC;                 // ~77K
    const int nbS = (scanLen + 255) / 256;       // <=1024

    // workspace layout (4B units)
    float*        norm_src = (float*)d_ws;                    // N
    float*        normd    = norm_src + N;                    // N
    unsigned int* cntg     = (unsigned int*)(normd + N);      // N
    unsigned int* offsets  = cntg + N;                        // N
    unsigned int* cnt8s    = offsets + N;                     // 8N (zeroed)
    unsigned int* gHist    = cnt8s + 8 * (size_t)N;           // scanLen
    unsigned int* scanA    = gHist + scanLen;                 // scanLen
    unsigned int* bsum     = scanA + scanLen;                 // 1024
    unsigned int* boff     = bsum + 1024;                     // 1024
    unsigned int* packed   = boff + 1024;                     // E
    int*          sorted   = (int*)(packed + E);              // E
    _Float16*     h        = (_Float16*)(sorted + E);         // NP*HD fp16
    _Float16*     xh       = h + (size_t)NP * HD;             // NP*HD fp16
    _Float16*     Wt       = xh + (size_t)NP * HD;            // 2*HD*HD fp16

    // ---- norms + weight transpose + bucket sort (shared by both layers) ----
    hipMemsetAsync(cnt8s, 0, (size_t)8 * N * 4, stream);
    hist_prep<<<NC + 2, 512, 0, stream>>>(dst, gHist, W1, W2, Wt, NB, NC, E);
    scan_a<<<nbS, 256, 0, stream>>>(gHist, scanA, bsum, scanLen);
    scan_b<<<1, 1024, 0, stream>>>(bsum, boff, nbS);
    scatter_coarse<<<NC, 512, 0, stream>>>(src, dst, scanA, boff, packed, cnt8s, N, NB, NC, E);
    fine_sort<<<NB, 256, 0, stream>>>(packed, scanA, boff, cnt8s, sorted, offsets, cntg,
                                      normd, norm_src, NB, NC, N, E);

    // ---- layer 1 (prep fused into gemm) ----
    gemm_mfma_f32<<<NP / 64, 256, 0, stream>>>(x, norm_src, Wt, h, N);
    aggregate_k<true><<<(N + 3) / 4, 256, 0, stream>>>((const __half*)h, sorted, offsets, cntg,
                                                       normd, norm_src, b1, nullptr,
                                                       (__half*)xh, N);

    // ---- layer 2 ----
    gemm_mfma<<<NP / 64, 256, 0, stream>>>(xh, Wt + HD * HD, h, N);
    aggregate_k<false><<<(N + 3) / 4, 256, 0, stream>>>((const __half*)h, sorted, offsets, cntg,
                                                        normd, nullptr, b2, out, nullptr, N);
}